// Round 5
// baseline (12524.174 us; speedup 1.0000x reference)
//
#include <hip/hip_runtime.h>
#include <stdint.h>

// LSTMClassifier: 2-layer LSTM (B=128,T=1024,I=256,H=512) + FC(512->1).
// Persistent grid-resident kernel. R10 = R9 schedule with the l1 poll
// threshold fixed. Data path = R6 exactly (proven fastest): linear h layout,
// 8B relaxed SYSTEM-scope atomic loads (sc0 sc1 -> IF$-coherent), scattered
// paired 4B atomic stores, no fences.
// Schedule: 4-deep ring per layer; l1 lags 2 steps; per-wave mid-iter poll;
// 2 barriers/step. Poll thresholds (own slot masked):
//   l0 @ s: l0 peers >= s   (true edge: h0(s-1)),  l1 peers >= s-1 (ring)
//   l1 @ s: l1 peers >= s   (true edge: h1(s-3)),  l0 peers >= s-1 (h0(s-2))
// R9's bug: l1 required only >= s-1 of its own layer -> stale h1(s-3).
// A layer's own recurrence is lag-1 regardless of cross-layer phase offset.
// Ring safety audit (all cases):
//   l0@s writes h0(s) slot s&3, destroys h0(s-4): read by l0@s-3 (l0>=s ✓)
//     and l1@s-2 (l1>=s-1 ✓).
//   l1@s writes h1(s-2), destroys h1(s-6): read by l1@s-3 (l1>=s ✓).
//   l0@s+2 destroys h0(s-2) read by l1@s: l0@s+2 polls l1>=s+1 ✓.
//
// ws layout (bytes):
//   Wp0 [2048][768]  bf16 packed rows r=u*4+q  (cols: 0..255=W_ih0, 256..767=W_hh0)
//   Wp1 [2048][1024] bf16 packed                (cols: 0..511=W_ih1, 512..1023=W_hh1)
//   bp0/bp1 [2048] f32 (b_ih+b_hh, packed order)
//   h    ushort[8][128*512]: h0 ring slots 0..3, then h1 ring slots 0..3
//   cnt  barrier slots: 8 groups x 64 dwords (one single-writer slot per block)

#define T_STEPS 1024
#define NBLK 512
#define NTHR 256

#define WS_WP0   0u
#define WS_WP1   3145728u
#define WS_BP0   7340032u
#define WS_BP1   7348224u
#define WS_H     7356416u
#define WS_CNT   8404992u
#define CNT_U32  512         // 8 groups x 64 slots

typedef __bf16 bf16x8 __attribute__((ext_vector_type(8)));
typedef float  f32x4  __attribute__((ext_vector_type(4)));
typedef unsigned long long ull;
typedef ull u64x2 __attribute__((ext_vector_type(2)));

__device__ __forceinline__ unsigned short f2bf(float f) {
    union { float f; uint32_t u; } a; a.f = f;
    uint32_t r = a.u + 0x7fffu + ((a.u >> 16) & 1u);
    return (unsigned short)(r >> 16);
}
__device__ __forceinline__ float bf2f(unsigned short u) {
    union { uint32_t u; float f; } a; a.u = ((uint32_t)u) << 16; return a.f;
}
__device__ __forceinline__ float sigm(float x)  { return 1.f / (1.f + __expf(-x)); }
__device__ __forceinline__ float tanh_f(float x){ return 2.f / (1.f + __expf(-2.f * x)) - 1.f; }

// IF$-coherent (L1+L2-bypassing) accessors: relaxed system atomics -> sc0 sc1
__device__ __forceinline__ bf16x8 ld_h16(const unsigned short* p) {
    u64x2 t;
    t.x = __hip_atomic_load((const ull*)p,       __ATOMIC_RELAXED, __HIP_MEMORY_SCOPE_SYSTEM);
    t.y = __hip_atomic_load((const ull*)(p + 4), __ATOMIC_RELAXED, __HIP_MEMORY_SCOPE_SYSTEM);
    return __builtin_bit_cast(bf16x8, t);
}
__device__ __forceinline__ void st_sys_u32(unsigned* p, unsigned v) {
    __hip_atomic_store(p, v, __ATOMIC_RELAXED, __HIP_MEMORY_SCOPE_SYSTEM);
}
__device__ __forceinline__ unsigned ld_sys_u32(const unsigned* p) {
    return __hip_atomic_load(p, __ATOMIC_RELAXED, __HIP_MEMORY_SCOPE_SYSTEM);
}

// ---- pre-pack weights to bf16, gate-interleaved rows r = u*4 + q (q: i,f,g,o) ----
__global__ void k_pack(const float* __restrict__ Wih0, const float* __restrict__ Whh0,
                       const float* __restrict__ Wih1, const float* __restrict__ Whh1,
                       unsigned short* __restrict__ Wp0, unsigned short* __restrict__ Wp1)
{
    int t = blockIdx.x * blockDim.x + threadIdx.x;
    const int N0 = 2048 * 768;
    const int N1 = 2048 * 1024;
    if (t < N0) {
        int r = t / 768, k = t - r * 768;
        int u = r >> 2, q = r & 3, row = q * 512 + u;
        float v = (k < 256) ? Wih0[row * 256 + k] : Whh0[row * 512 + (k - 256)];
        Wp0[t] = f2bf(v);
    } else if (t < N0 + N1) {
        int t2 = t - N0;
        int r = t2 >> 10, k = t2 & 1023;
        int u = r >> 2, q = r & 3, row = q * 512 + u;
        float v = (k < 512) ? Wih1[row * 512 + k] : Whh1[row * 512 + (k - 512)];
        Wp1[t2] = f2bf(v);
    }
}

// ---- biases (packed), zero h ring buffers, zero barrier slots ----
__global__ void k_misc(const float* __restrict__ bih0, const float* __restrict__ bhh0,
                       const float* __restrict__ bih1, const float* __restrict__ bhh1,
                       float* __restrict__ bp0, float* __restrict__ bp1,
                       unsigned short* __restrict__ hbufs, unsigned* __restrict__ cnt)
{
    int t = blockIdx.x * blockDim.x + threadIdx.x;
    if (t < 2048) {
        int u = t >> 2, q = t & 3, row = q * 512 + u;
        bp0[t] = bih0[row] + bhh0[row];
    } else if (t < 4096) {
        int r = t - 2048; int u = r >> 2, q = r & 3, row = q * 512 + u;
        bp1[r] = bih1[row] + bhh1[row];
    } else if (t < 4096 + 524288) {
        hbufs[t - 4096] = 0;
    } else if (t < 4096 + 524288 + CNT_U32) {
        cnt[t - (4096 + 524288)] = 0;
    }
}

// ---- persistent LSTM ----
// NKW: ksteps per wave; KTOT: total K; KS: boundary src0/src1; L0: layer-0 flag
// h rings: h0(t) at hb + (t&3)*65536, h1(t) at hb + 262144 + (t&3)*65536
template<int NKW, int KTOT, int KS, bool L0>
__device__ __forceinline__ void run_layer(
    int b0, int ut0, int g0, int w, int col, int quad, int tid,
    const float* __restrict__ x,
    const unsigned short* __restrict__ Wp,
    const float* __restrict__ bp,
    unsigned short* __restrict__ hb,
    unsigned* slots, int myslot,
    float (*red)[16][68])
{
    const int bA   = b0 + col;  // A-fragment row (batch index)
    const int lane = tid & 63;

    // B fragments (weights) -> register-resident for the whole run (pinned).
    uint4 Bf[4][NKW];
    #pragma unroll
    for (int f = 0; f < 4; ++f) {
        const unsigned short* wrow = Wp + (g0 + f * 16 + col) * KTOT + w * (NKW * 32) + quad * 8;
        #pragma unroll
        for (int ks = 0; ks < NKW; ++ks)
            Bf[f][ks] = *(const uint4*)(wrow + ks * 32);
    }
    #pragma unroll
    for (int f = 0; f < 4; ++f) {
        #pragma unroll
        for (int ks = 0; ks < NKW; ++ks) {
            uint32_t c0 = Bf[f][ks].x, c1 = Bf[f][ks].y, c2 = Bf[f][ks].z, c3 = Bf[f][ks].w;
            asm volatile("" : "+v"(c0), "+v"(c1), "+v"(c2), "+v"(c3));
            Bf[f][ks].x = c0; Bf[f][ks].y = c1; Bf[f][ks].z = c2; Bf[f][ks].w = c3;
        }
    }

    const int bl = tid >> 4, ul = tid & 15;      // elementwise domain: 16 batch x 16 units
    const f32x4 bias = *(const f32x4*)(bp + g0 + ul * 4);
    float c = 0.f;                               // cell state, register-resident

    // Per-kstep A source offsets (frag never straddles the KS boundary: 32 | KS)
    int  offA[NKW];
    bool s0[NKW];
    #pragma unroll
    for (int ks = 0; ks < NKW; ++ks) {
        int kg = w * (NKW * 32) + ks * 32 + quad * 8;
        if (kg < KS) { s0[ks] = true;  offA[ks] = L0 ? (bA * (T_STEPS * 256) + kg) : (bA * 512 + kg); }
        else         { s0[ks] = false; offA[ks] = bA * 512 + (kg - KS); }
    }

    const int SMAX = L0 ? (T_STEPS - 1) : (T_STEPS + 1);

    for (int s = 0; s <= SMAX; ++s) {
        const bool active = L0 || (s >= 2);      // l1 computes t = s-2
        bf16x8 Af[NKW];

        if (L0) {
            // x-part: static data, issue before the poll (overlaps detect+trip)
            const float* xb = x + s * 256;
            #pragma unroll
            for (int ks = 0; ks < NKW; ++ks) {
                if (s0[ks]) {
                    const float* p = xb + offA[ks];
                    float4 lo = *(const float4*)p;
                    float4 hi = *(const float4*)(p + 4);
                    bf16x8 v;
                    v[0]=(__bf16)lo.x; v[1]=(__bf16)lo.y; v[2]=(__bf16)lo.z; v[3]=(__bf16)lo.w;
                    v[4]=(__bf16)hi.x; v[5]=(__bf16)hi.y; v[6]=(__bf16)hi.z; v[7]=(__bf16)hi.w;
                    Af[ks] = v;
                }
            }
            // poll: l0 peers (even slots) >= s [true edge: h0(s-1)],
            //       l1 peers (odd slots)  >= s-1 [ring slack]. Own slot masked.
            int tgt = s - (lane & 1);
            if (lane == myslot) tgt = (int)0x80000000;
            for (;;) {
                int v = (int)ld_sys_u32(slots + lane);
                if (__all(v >= tgt)) break;
                __builtin_amdgcn_s_sleep(1);
            }
            asm volatile("" ::: "memory");
            // h0(s-1) loads
            const unsigned short* hr = hb + (((unsigned)(s + 3)) & 3u) * 65536;
            #pragma unroll
            for (int ks = 0; ks < NKW; ++ks)
                if (!s0[ks]) Af[ks] = ld_h16(hr + offA[ks]);
        } else {
            // poll: l1 peers (odd slots) >= s [true edge: h1(s-3), produced by
            //       peers at iter s-1 -> flag s],
            //       l0 peers (even slots) >= s-1 [h0(s-2) ready]. Own masked.
            int tgt = s - 1 + (lane & 1);
            if (lane == myslot) tgt = (int)0x80000000;
            for (;;) {
                int v = (int)ld_sys_u32(slots + lane);
                if (__all(v >= tgt)) break;
                __builtin_amdgcn_s_sleep(1);
            }
            asm volatile("" ::: "memory");
            if (active) {
                const unsigned short* h0r = hb + (((unsigned)(s - 2)) & 3u) * 65536;
                const unsigned short* h1r = hb + 262144 + (((unsigned)(s + 1)) & 3u) * 65536; // (s-3)&3
                #pragma unroll
                for (int ks = 0; ks < NKW; ++ks)
                    Af[ks] = ld_h16((s0[ks] ? h0r : h1r) + offA[ks]);
            }
        }

        if (active) {
            f32x4 acc[4] = { f32x4{0,0,0,0}, f32x4{0,0,0,0}, f32x4{0,0,0,0}, f32x4{0,0,0,0} };
            #pragma unroll
            for (int ks = 0; ks < NKW; ++ks) {
                #pragma unroll
                for (int f = 0; f < 4; ++f)
                    acc[f] = __builtin_amdgcn_mfma_f32_16x16x32_bf16(
                        Af[ks], __builtin_bit_cast(bf16x8, Bf[f][ks]), acc[f], 0, 0, 0);
            }
            // Dump partials: D row=quad*4+r (batch), col=f*16+col (packed gate)
            #pragma unroll
            for (int f = 0; f < 4; ++f) {
                #pragma unroll
                for (int r = 0; r < 4; ++r)
                    red[w][quad * 4 + r][f * 16 + col] = acc[f][r];
            }
        }
        __syncthreads();
        if (active) {
            f32x4 g = bias;
            #pragma unroll
            for (int ww = 0; ww < 4; ++ww)
                g += *(const f32x4*)&red[ww][bl][ul * 4];
            float ig = sigm(g[0]), fg = sigm(g[1]), gc = tanh_f(g[2]), og = sigm(g[3]);
            c = fg * c + ig * gc;
            float h = og * tanh_f(c);
            // pack adjacent ul lanes -> one 4B IF$-coherent store per pair
            unsigned short hv = f2bf(h);
            unsigned short pv = (unsigned short)__shfl_xor((int)hv, 1);
            if (!(ul & 1)) {
                unsigned short* hw = L0
                    ? (hb + (((unsigned)s) & 3u) * 65536)                       // h0(s)
                    : (hb + 262144 + (((unsigned)(s - 2)) & 3u) * 65536);       // h1(s-2)
                unsigned pk = (unsigned)hv | ((unsigned)pv << 16);
                st_sys_u32((unsigned*)(hw + (b0 + bl) * 512 + ut0 + ul), pk);
            }
        }
        // release: drain own vmem (stores acked at IF$), then post flag
        asm volatile("s_waitcnt vmcnt(0)" ::: "memory");
        __syncthreads();
        if (tid == 0)
            st_sys_u32(slots + myslot, (unsigned)(s + 1));
    }
}

__global__ __launch_bounds__(NTHR, 2) void lstm_persistent(
    const float* __restrict__ x,
    const unsigned short* __restrict__ Wp0, const unsigned short* __restrict__ Wp1,
    const float* __restrict__ bp0, const float* __restrict__ bp1,
    unsigned short* __restrict__ hb, unsigned* __restrict__ cnt)
{
    __shared__ alignas(16) float red[4][16][68];   // 4 K-split waves x [16b][64g(+pad)]
    const int bid   = blockIdx.x;
    const int g     = bid & 7;          // batch-tile group (independent barrier domain)
    const int rest  = bid >> 3;         // 0..63: pid within group
    const int layer = rest & 1;
    const int ut    = rest >> 1;        // 0..31 unit-tile
    const int b0    = g * 16;
    const int ut0   = ut * 16;
    const int g0    = ut * 64;          // packed gate-row base (= ut0*4)
    const int tid   = threadIdx.x;
    const int w = tid >> 6, lane = tid & 63, col = lane & 15, quad = lane >> 4;

    unsigned* slots = cnt + g * 64;
    const int myslot = rest;

    if (layer == 0)
        run_layer<6, 768, 256, true >(b0, ut0, g0, w, col, quad, tid, x, Wp0, bp0, hb, slots, myslot, red);
    else
        run_layer<8, 1024, 512, false>(b0, ut0, g0, w, col, quad, tid, x, Wp1, bp1, hb, slots, myslot, red);
}

// ---- final FC head: logits[b] = h1_T[b,:] . fc_w + fc_b ----
// final h1(1023) lives in h1 ring slot 1023&3 = 3
__global__ void k_fc(const unsigned short* __restrict__ h1, const float* __restrict__ fcw,
                     const float* __restrict__ fcb, float* __restrict__ out)
{
    int b = threadIdx.x;
    if (b < 128) {
        const unsigned short* hr = h1 + b * 512;
        float acc = 0.f;
        for (int u = 0; u < 512; ++u) acc += bf2f(hr[u]) * fcw[u];
        out[b] = acc + fcb[0];
    }
}

extern "C" void kernel_launch(void* const* d_in, const int* in_sizes, int n_in,
                              void* d_out, int out_size, void* d_ws, size_t ws_size,
                              hipStream_t stream)
{
    const float* x    = (const float*)d_in[0];
    const float* Wih0 = (const float*)d_in[1];
    const float* Whh0 = (const float*)d_in[2];
    const float* bih0 = (const float*)d_in[3];
    const float* bhh0 = (const float*)d_in[4];
    const float* Wih1 = (const float*)d_in[5];
    const float* Whh1 = (const float*)d_in[6];
    const float* bih1 = (const float*)d_in[7];
    const float* bhh1 = (const float*)d_in[8];
    const float* fcw  = (const float*)d_in[9];
    const float* fcb  = (const float*)d_in[10];

    char* ws = (char*)d_ws;
    unsigned short* Wp0 = (unsigned short*)(ws + WS_WP0);
    unsigned short* Wp1 = (unsigned short*)(ws + WS_WP1);
    float* bp0 = (float*)(ws + WS_BP0);
    float* bp1 = (float*)(ws + WS_BP1);
    unsigned short* hb = (unsigned short*)(ws + WS_H);
    unsigned* cnt = (unsigned*)(ws + WS_CNT);

    const int npack = 2048 * 768 + 2048 * 1024;
    k_pack<<<(npack + 255) / 256, 256, 0, stream>>>(Wih0, Whh0, Wih1, Whh1, Wp0, Wp1);
    const int nmisc = 4096 + 524288 + CNT_U32;
    k_misc<<<(nmisc + 255) / 256, 256, 0, stream>>>(bih0, bhh0, bih1, bhh1, bp0, bp1, hb, cnt);

    lstm_persistent<<<NBLK, NTHR, 0, stream>>>(x, Wp0, Wp1, bp0, bp1, hb, cnt);

    // final h1(1023) is in h1 ring slot 3: hb + 262144 + 3*65536
    k_fc<<<1, 128, 0, stream>>>(hb + 262144 + 196608, fcw, fcb, (float*)d_out);
}

// Round 6
// 9586.855 us; speedup vs baseline: 1.3064x; 1.3064x over previous
//
#include <hip/hip_runtime.h>
#include <stdint.h>

// LSTMClassifier: 2-layer LSTM (B=128,T=1024,I=256,H=512) + FC(512->1).
// Persistent grid-resident kernel, layers pipelined (layer1 lags 1 step).
// R11 = R6 protocol EXACTLY (proven fastest: 2-deep ping-pong, full 64-slot
// rendezvous, ONE polling wave per block, relaxed SYSTEM-scope atomics ->
// sc0 sc1 IF$-coherent, no fences) + dense LDS-staged h loads:
//   - each block stages its group's h slice (16KB/buffer, contiguous rows)
//     into LDS with 16B/lane coherent loads: 128 dense line-requests per
//     16KB vs ~1024 sparse ones for the old strided 8B fragment loads
//     (~8x fewer IF$ transactions; R6's measured residual bottleneck).
//   - MFMA A-fragments read from LDS via ds_read_b128 with XOR swizzle
//     (byte ^= (row&7)<<4 on BOTH write and read) to kill the 16-way bank
//     conflict of the 1KB row stride.
// Lessons encoded: R7 (XCD-local L2) and R10 (4-wave poll) both regressed by
// saturating one coherence point -> keep 1-wave poll + IF$ scope. R9's bug:
// a layer's own recurrence is lag-1 regardless of cross-layer phase.
//
// ws layout (bytes):
//   Wp0 [2048][768]  bf16 packed rows r=u*4+q  (cols: 0..255=W_ih0, 256..767=W_hh0)
//   Wp1 [2048][1024] bf16 packed                (cols: 0..511=W_ih1, 512..1023=W_hh1)
//   bp0/bp1 [2048] f32 (b_ih+b_hh, packed order)
//   h    ushort[4][128*512]: h0[0],h0[1],h1[0],h1[1] (ping-pong per macro-step)
//   cnt  barrier slots: 8 groups x 64 dwords (one single-writer slot per block)

#define T_STEPS 1024
#define NBLK 512
#define NTHR 256

#define WS_WP0   0u
#define WS_WP1   3145728u
#define WS_BP0   7340032u
#define WS_BP1   7348224u
#define WS_H     7356416u
#define WS_CNT   7880704u
#define CNT_U32  512         // 8 groups x 64 slots

typedef __bf16 bf16x8 __attribute__((ext_vector_type(8)));
typedef float  f32x4  __attribute__((ext_vector_type(4)));
typedef unsigned long long ull;
typedef ull u64x2 __attribute__((ext_vector_type(2)));

__device__ __forceinline__ unsigned short f2bf(float f) {
    union { float f; uint32_t u; } a; a.f = f;
    uint32_t r = a.u + 0x7fffu + ((a.u >> 16) & 1u);
    return (unsigned short)(r >> 16);
}
__device__ __forceinline__ float bf2f(unsigned short u) {
    union { uint32_t u; float f; } a; a.u = ((uint32_t)u) << 16; return a.f;
}
__device__ __forceinline__ float sigm(float x)  { return 1.f / (1.f + __expf(-x)); }
__device__ __forceinline__ float tanh_f(float x){ return 2.f / (1.f + __expf(-2.f * x)) - 1.f; }

// IF$-coherent (L1+L2-bypassing) accessors: relaxed system atomics -> sc0 sc1
__device__ __forceinline__ ull ld_sys_u64(const ull* p) {
    return __hip_atomic_load(p, __ATOMIC_RELAXED, __HIP_MEMORY_SCOPE_SYSTEM);
}
__device__ __forceinline__ void st_sys_u32(unsigned* p, unsigned v) {
    __hip_atomic_store(p, v, __ATOMIC_RELAXED, __HIP_MEMORY_SCOPE_SYSTEM);
}
__device__ __forceinline__ unsigned ld_sys_u32(const unsigned* p) {
    return __hip_atomic_load(p, __ATOMIC_RELAXED, __HIP_MEMORY_SCOPE_SYSTEM);
}

// ---- pre-pack weights to bf16, gate-interleaved rows r = u*4 + q (q: i,f,g,o) ----
__global__ void k_pack(const float* __restrict__ Wih0, const float* __restrict__ Whh0,
                       const float* __restrict__ Wih1, const float* __restrict__ Whh1,
                       unsigned short* __restrict__ Wp0, unsigned short* __restrict__ Wp1)
{
    int t = blockIdx.x * blockDim.x + threadIdx.x;
    const int N0 = 2048 * 768;
    const int N1 = 2048 * 1024;
    if (t < N0) {
        int r = t / 768, k = t - r * 768;
        int u = r >> 2, q = r & 3, row = q * 512 + u;
        float v = (k < 256) ? Wih0[row * 256 + k] : Whh0[row * 512 + (k - 256)];
        Wp0[t] = f2bf(v);
    } else if (t < N0 + N1) {
        int t2 = t - N0;
        int r = t2 >> 10, k = t2 & 1023;
        int u = r >> 2, q = r & 3, row = q * 512 + u;
        float v = (k < 512) ? Wih1[row * 512 + k] : Whh1[row * 512 + (k - 512)];
        Wp1[t2] = f2bf(v);
    }
}

// ---- biases (packed), zero h ping-pong buffers, zero barrier slots ----
__global__ void k_misc(const float* __restrict__ bih0, const float* __restrict__ bhh0,
                       const float* __restrict__ bih1, const float* __restrict__ bhh1,
                       float* __restrict__ bp0, float* __restrict__ bp1,
                       unsigned short* __restrict__ hbufs, unsigned* __restrict__ cnt)
{
    int t = blockIdx.x * blockDim.x + threadIdx.x;
    if (t < 2048) {
        int u = t >> 2, q = t & 3, row = q * 512 + u;
        bp0[t] = bih0[row] + bhh0[row];
    } else if (t < 4096) {
        int r = t - 2048; int u = r >> 2, q = r & 3, row = q * 512 + u;
        bp1[r] = bih1[row] + bhh1[row];
    } else if (t < 4096 + 262144) {
        hbufs[t - 4096] = 0;
    } else if (t < 4096 + 262144 + CNT_U32) {
        cnt[t - (4096 + 262144)] = 0;
    }
}

// Stage one 16KB h slice (group rows are contiguous: 16 rows x 1KB) into LDS
// with the (row&7)<<4 byte XOR swizzle. 256 threads x 4 rounds x 16B.
// Each wave covers exactly one row per round -> swizzle uniform -> dense,
// conflict-free ds_write_b128; global side fully coalesced (1KB/wave).
#define STAGE16(dstbase, srcbase, tid)                                      \
    do {                                                                    \
        _Pragma("unroll")                                                   \
        for (int i_ = 0; i_ < 4; ++i_) {                                    \
            int off_ = i_ * 4096 + (tid) * 16;                              \
            int swz_ = (off_ & ~1023) |                                     \
                       ((off_ & 1023) ^ (((off_ >> 10) & 7) << 4));         \
            u64x2 v_;                                                       \
            v_.x = ld_sys_u64((const ull*)((srcbase) + off_));              \
            v_.y = ld_sys_u64((const ull*)((srcbase) + off_ + 8));          \
            *(u64x2*)((dstbase) + swz_) = v_;                               \
        }                                                                   \
    } while (0)

// ---- persistent LSTM ----
// NKW: ksteps per wave; KTOT: total K; KS: boundary src0/src1; L0: layer-0 flag
template<int NKW, int KTOT, int KS, bool L0>
__device__ __forceinline__ void run_layer(
    int b0, int ut0, int g0, int w, int col, int quad, int tid,
    const float* __restrict__ x,
    const unsigned short* __restrict__ Wp,
    const float* __restrict__ bp,
    unsigned short* h00, unsigned short* h01,
    unsigned short* h10, unsigned short* h11,
    unsigned* slots, int myslot,
    float (*red)[16][68], unsigned short (*shh)[512])
{
    const int bA = b0 + col;  // A-fragment row (batch index)

    // B fragments (weights) -> register-resident for the whole run (pinned).
    uint4 Bf[4][NKW];
    #pragma unroll
    for (int f = 0; f < 4; ++f) {
        const unsigned short* wrow = Wp + (g0 + f * 16 + col) * KTOT + w * (NKW * 32) + quad * 8;
        #pragma unroll
        for (int ks = 0; ks < NKW; ++ks)
            Bf[f][ks] = *(const uint4*)(wrow + ks * 32);
    }
    #pragma unroll
    for (int f = 0; f < 4; ++f) {
        #pragma unroll
        for (int ks = 0; ks < NKW; ++ks) {
            uint32_t c0 = Bf[f][ks].x, c1 = Bf[f][ks].y, c2 = Bf[f][ks].z, c3 = Bf[f][ks].w;
            asm volatile("" : "+v"(c0), "+v"(c1), "+v"(c2), "+v"(c3));
            Bf[f][ks].x = c0; Bf[f][ks].y = c1; Bf[f][ks].z = c2; Bf[f][ks].w = c3;
        }
    }

    const int bl = tid >> 4, ul = tid & 15;      // elementwise domain: 16 batch x 16 units
    const f32x4 bias = *(const f32x4*)(bp + g0 + ul * 4);
    float c = 0.f;                               // cell state, register-resident

    // Per-kstep A sources. x fragments: global fp32 (layer 0, kg<KS).
    // h fragments: LDS byte offset (buffer sel + row=col + swizzled column).
    int  offX[NKW];   // global float index for x fragments
    int  offL[NKW];   // LDS byte offset for h fragments
    bool isx[NKW];
    #pragma unroll
    for (int ks = 0; ks < NKW; ++ks) {
        int kg = w * (NKW * 32) + ks * 32 + quad * 8;
        if (L0 && kg < KS) {
            isx[ks] = true;
            offX[ks] = bA * (T_STEPS * 256) + kg;
            offL[ks] = 0;
        } else {
            isx[ks] = false;
            int buf, u;
            if (L0)           { buf = 0; u = kg - KS; }     // h0 part
            else if (kg < KS) { buf = 0; u = kg; }          // h0 part
            else              { buf = 1; u = kg - KS; }     // h1 part
            offL[ks] = buf * 16384 + col * 1024 + ((2 * u) ^ ((col & 7) << 4));
            offX[ks] = 0;
        }
    }

    unsigned short* h0b[2] = { h00, h01 };
    unsigned short* h1b[2] = { h10, h11 };
    int rp = 0;
    char* shb = (char*)shh;

    for (int s = 0; s <= T_STEPS; ++s) {
        const bool active = L0 ? (s < T_STEPS) : (s >= 1);
        const char* h0src = (const char*)h0b[rp] + b0 * 1024;  // group slice, contiguous 16KB
        const char* h1src = (const char*)h1b[rp] + b0 * 1024;

        bf16x8 Af[NKW];
        if (active) {
            if (L0) {
                // x-part: plain cached loads, fp32 -> bf16 on the fly
                const float* xb = x + s * 256;
                #pragma unroll
                for (int ks = 0; ks < NKW; ++ks) {
                    if (isx[ks]) {
                        const float* p = xb + offX[ks];
                        float4 lo = *(const float4*)p;
                        float4 hi = *(const float4*)(p + 4);
                        bf16x8 v;
                        v[0]=(__bf16)lo.x; v[1]=(__bf16)lo.y; v[2]=(__bf16)lo.z; v[3]=(__bf16)lo.w;
                        v[4]=(__bf16)hi.x; v[5]=(__bf16)hi.y; v[6]=(__bf16)hi.z; v[7]=(__bf16)hi.w;
                        Af[ks] = v;
                    }
                }
                STAGE16(shb, h0src, tid);                    // h0(s-1) -> LDS buf 0
            } else {
                STAGE16(shb, h0src, tid);                    // h0(s-1) -> LDS buf 0
                STAGE16(shb + 16384, h1src, tid);            // h1(s-2) -> LDS buf 1
            }
        }
        __syncthreads();   // LDS staged (drains vm+lgkm for all waves)

        if (active) {
            #pragma unroll
            for (int ks = 0; ks < NKW; ++ks)
                if (!isx[ks])
                    Af[ks] = *(const bf16x8*)(shb + offL[ks]);   // ds_read_b128, swizzled

            f32x4 acc[4] = { f32x4{0,0,0,0}, f32x4{0,0,0,0}, f32x4{0,0,0,0}, f32x4{0,0,0,0} };
            #pragma unroll
            for (int ks = 0; ks < NKW; ++ks) {
                #pragma unroll
                for (int f = 0; f < 4; ++f)
                    acc[f] = __builtin_amdgcn_mfma_f32_16x16x32_bf16(
                        Af[ks], __builtin_bit_cast(bf16x8, Bf[f][ks]), acc[f], 0, 0, 0);
            }
            // Dump partials: D row=quad*4+r (batch), col=f*16+col (packed gate)
            #pragma unroll
            for (int f = 0; f < 4; ++f) {
                #pragma unroll
                for (int r = 0; r < 4; ++r)
                    red[w][quad * 4 + r][f * 16 + col] = acc[f][r];
            }
        }
        __syncthreads();
        if (active) {
            f32x4 g = bias;
            #pragma unroll
            for (int ww = 0; ww < 4; ++ww)
                g += *(const f32x4*)&red[ww][bl][ul * 4];
            float ig = sigm(g[0]), fg = sigm(g[1]), gc = tanh_f(g[2]), og = sigm(g[3]);
            c = fg * c + ig * gc;
            float h = og * tanh_f(c);
            // pack adjacent ul lanes -> one 4B IF$-coherent store per pair
            unsigned short hv = f2bf(h);
            unsigned short pv = (unsigned short)__shfl_xor((int)hv, 1);
            if (!(ul & 1)) {
                unsigned short* hw = L0 ? h0b[rp ^ 1] : h1b[rp ^ 1];
                unsigned pk = (unsigned)hv | ((unsigned)pv << 16);
                st_sys_u32((unsigned*)(hw + (b0 + bl) * 512 + ut0 + ul), pk);
            }
        }
        // release: drain own vmem (h stores acked at IF$), then post flag
        asm volatile("s_waitcnt vmcnt(0)" ::: "memory");
        __syncthreads();
        // ONE relaxed flag store per block (sc0 sc1 -> IF$)
        if (tid == 0)
            st_sys_u32(slots + myslot, (unsigned)(s + 1));
        // wave0 ONLY: parallel poll of all 64 group slots (2 cache lines).
        // (R10 proved 4-wave polling saturates the hot flag lines.)
        if (tid < 64) {
            const unsigned tgt = (unsigned)(s + 1);
            for (;;) {
                unsigned v = ld_sys_u32(slots + tid);
                if (__all((int)(v >= tgt))) break;
                __builtin_amdgcn_s_sleep(1);
            }
        }
        asm volatile("" ::: "memory");
        __syncthreads();
        rp ^= 1;
    }
}

__global__ __launch_bounds__(NTHR, 2) void lstm_persistent(
    const float* __restrict__ x,
    const unsigned short* __restrict__ Wp0, const unsigned short* __restrict__ Wp1,
    const float* __restrict__ bp0, const float* __restrict__ bp1,
    unsigned short* __restrict__ hb, unsigned* __restrict__ cnt)
{
    __shared__ alignas(16) float red[4][16][68];            // 17408B reduction buffer
    __shared__ alignas(16) unsigned short shh[2][16][512];  // 32KB staged h (l0 uses [0])
    const int bid   = blockIdx.x;
    const int g     = bid & 7;          // batch-tile group (independent barrier domain)
    const int rest  = bid >> 3;         // 0..63: pid within group
    const int layer = rest & 1;
    const int ut    = rest >> 1;        // 0..31 unit-tile
    const int b0    = g * 16;
    const int ut0   = ut * 16;
    const int g0    = ut * 64;          // packed gate-row base (= ut0*4)
    const int tid   = threadIdx.x;
    const int w = tid >> 6, lane = tid & 63, col = lane & 15, quad = lane >> 4;

    unsigned* slots = cnt + g * 64;
    const int myslot = rest;

    unsigned short* h00 = hb;
    unsigned short* h01 = hb + 65536;
    unsigned short* h10 = hb + 131072;
    unsigned short* h11 = hb + 196608;

    if (layer == 0)
        run_layer<6, 768, 256, true >(b0, ut0, g0, w, col, quad, tid, x, Wp0, bp0, h00, h01, h10, h11, slots, myslot, red, (unsigned short (*)[512])shh);
    else
        run_layer<8, 1024, 512, false>(b0, ut0, g0, w, col, quad, tid, x, Wp1, bp1, h00, h01, h10, h11, slots, myslot, red, (unsigned short (*)[512])shh);
}

// ---- final FC head: logits[b] = h1_T[b,:] . fc_w + fc_b ----
__global__ void k_fc(const unsigned short* __restrict__ h1, const float* __restrict__ fcw,
                     const float* __restrict__ fcb, float* __restrict__ out)
{
    int b = threadIdx.x;
    if (b < 128) {
        const unsigned short* hr = h1 + b * 512;
        float acc = 0.f;
        for (int u = 0; u < 512; ++u) acc += bf2f(hr[u]) * fcw[u];
        out[b] = acc + fcb[0];
    }
}

extern "C" void kernel_launch(void* const* d_in, const int* in_sizes, int n_in,
                              void* d_out, int out_size, void* d_ws, size_t ws_size,
                              hipStream_t stream)
{
    const float* x    = (const float*)d_in[0];
    const float* Wih0 = (const float*)d_in[1];
    const float* Whh0 = (const float*)d_in[2];
    const float* bih0 = (const float*)d_in[3];
    const float* bhh0 = (const float*)d_in[4];
    const float* Wih1 = (const float*)d_in[5];
    const float* Whh1 = (const float*)d_in[6];
    const float* bih1 = (const float*)d_in[7];
    const float* bhh1 = (const float*)d_in[8];
    const float* fcw  = (const float*)d_in[9];
    const float* fcb  = (const float*)d_in[10];

    char* ws = (char*)d_ws;
    unsigned short* Wp0 = (unsigned short*)(ws + WS_WP0);
    unsigned short* Wp1 = (unsigned short*)(ws + WS_WP1);
    float* bp0 = (float*)(ws + WS_BP0);
    float* bp1 = (float*)(ws + WS_BP1);
    unsigned short* hb = (unsigned short*)(ws + WS_H);
    unsigned* cnt = (unsigned*)(ws + WS_CNT);

    const int npack = 2048 * 768 + 2048 * 1024;
    k_pack<<<(npack + 255) / 256, 256, 0, stream>>>(Wih0, Whh0, Wih1, Whh1, Wp0, Wp1);
    const int nmisc = 4096 + 262144 + CNT_U32;
    k_misc<<<(nmisc + 255) / 256, 256, 0, stream>>>(bih0, bhh0, bih1, bhh1, bp0, bp1, hb, cnt);

    lstm_persistent<<<NBLK, NTHR, 0, stream>>>(x, Wp0, Wp1, bp0, bp1, hb, cnt);

    // final h1 lands in ping-pong buffer index 1 (written at macro-step s=1024)
    k_fc<<<1, 128, 0, stream>>>(hb + 196608, fcw, fcb, (float*)d_out);
}

// Round 8
// 8624.204 us; speedup vs baseline: 1.4522x; 1.1116x over previous
//
#include <hip/hip_runtime.h>
#include <stdint.h>

// LSTMClassifier: 2-layer LSTM (B=128,T=1024,I=256,H=512) + FC(512->1).
// Persistent grid-resident kernel, layers pipelined (layer1 lags 1 step).
// R13: R6 protocol byte-for-byte (proven fastest: 2-deep ping-pong, full
// rendezvous, relaxed SYSTEM-scope atomics -> sc0 sc1 IF$-coherent, no
// fences, tid0 flag, ONE polling wave, 3 barriers/step) + restructured
// compute:
//   - 512-thr/8-wave blocks (VGPR cap 256: l1 pins Bf[32]=128 regs safely;
//     R12's 16-wave/128-cap design spilled -> likely the container hang).
//   - each wave owns ONE N-tile x FULL K -> acc is the complete gate
//     preactivation; the LDS reduction buffer + its barrier are GONE.
//   - gates of a unit live in 4 adjacent lanes (packed rows u*4+q) ->
//     in-wave eltwise via shfl_xor(1,2,4); c-state replicated x4 in regs.
//   - block stages its group's h slice into LDS once (dense 16B/lane sc01
//     loads, XOR swizzle (row&7)<<4): IF$ h-volume 12MB->6MB/step; flags
//     512->256/step; rendezvous 64->32 slots (one cache line).
//   - LDS = 32KB static. No dynamic LDS, no hipFuncSetAttribute.
//
// ws layout (bytes): unchanged from R6.
//   Wp0 [2048][768]  bf16 packed rows r=u*4+q  (cols: 0..255=W_ih0, 256..767=W_hh0)
//   Wp1 [2048][1024] bf16 packed                (cols: 0..511=W_ih1, 512..1023=W_hh1)
//   bp0/bp1 [2048] f32; h ushort[4][128*512]; cnt 8 groups x 32 slots

#define T_STEPS 1024
#define NBLK 256
#define NTHR 512

#define WS_WP0   0u
#define WS_WP1   3145728u
#define WS_BP0   7340032u
#define WS_BP1   7348224u
#define WS_H     7356416u
#define WS_CNT   7880704u
#define CNT_U32  512

typedef __bf16 bf16x8 __attribute__((ext_vector_type(8)));
typedef float  f32x4  __attribute__((ext_vector_type(4)));
typedef unsigned long long ull;
typedef ull u64x2 __attribute__((ext_vector_type(2)));

__device__ __forceinline__ unsigned short f2bf(float f) {
    union { float f; uint32_t u; } a; a.f = f;
    uint32_t r = a.u + 0x7fffu + ((a.u >> 16) & 1u);
    return (unsigned short)(r >> 16);
}
__device__ __forceinline__ float bf2f(unsigned short u) {
    union { uint32_t u; float f; } a; a.u = ((uint32_t)u) << 16; return a.f;
}
__device__ __forceinline__ float sigm(float x)  { return 1.f / (1.f + __expf(-x)); }
__device__ __forceinline__ float tanh_f(float x){ return 2.f / (1.f + __expf(-2.f * x)) - 1.f; }

// IF$-coherent (L1+L2-bypassing) accessors: relaxed system atomics -> sc0 sc1
__device__ __forceinline__ ull ld_sys_u64(const ull* p) {
    return __hip_atomic_load(p, __ATOMIC_RELAXED, __HIP_MEMORY_SCOPE_SYSTEM);
}
__device__ __forceinline__ void st_sys_u32(unsigned* p, unsigned v) {
    __hip_atomic_store(p, v, __ATOMIC_RELAXED, __HIP_MEMORY_SCOPE_SYSTEM);
}
__device__ __forceinline__ unsigned ld_sys_u32(const unsigned* p) {
    return __hip_atomic_load(p, __ATOMIC_RELAXED, __HIP_MEMORY_SCOPE_SYSTEM);
}

// ---- pre-pack weights to bf16, gate-interleaved rows r = u*4 + q (q: i,f,g,o) ----
__global__ void k_pack(const float* __restrict__ Wih0, const float* __restrict__ Whh0,
                       const float* __restrict__ Wih1, const float* __restrict__ Whh1,
                       unsigned short* __restrict__ Wp0, unsigned short* __restrict__ Wp1)
{
    int t = blockIdx.x * blockDim.x + threadIdx.x;
    const int N0 = 2048 * 768;
    const int N1 = 2048 * 1024;
    if (t < N0) {
        int r = t / 768, k = t - r * 768;
        int u = r >> 2, q = r & 3, row = q * 512 + u;
        float v = (k < 256) ? Wih0[row * 256 + k] : Whh0[row * 512 + (k - 256)];
        Wp0[t] = f2bf(v);
    } else if (t < N0 + N1) {
        int t2 = t - N0;
        int r = t2 >> 10, k = t2 & 1023;
        int u = r >> 2, q = r & 3, row = q * 512 + u;
        float v = (k < 512) ? Wih1[row * 512 + k] : Whh1[row * 512 + (k - 512)];
        Wp1[t2] = f2bf(v);
    }
}

// ---- biases (packed), zero h ping-pong buffers, zero flag slots ----
__global__ void k_misc(const float* __restrict__ bih0, const float* __restrict__ bhh0,
                       const float* __restrict__ bih1, const float* __restrict__ bhh1,
                       float* __restrict__ bp0, float* __restrict__ bp1,
                       unsigned short* __restrict__ hbufs, unsigned* __restrict__ cnt)
{
    int t = blockIdx.x * blockDim.x + threadIdx.x;
    if (t < 2048) {
        int u = t >> 2, q = t & 3, row = q * 512 + u;
        bp0[t] = bih0[row] + bhh0[row];
    } else if (t < 4096) {
        int r = t - 2048; int u = r >> 2, q = r & 3, row = q * 512 + u;
        bp1[r] = bih1[row] + bhh1[row];
    } else if (t < 4096 + 262144) {
        hbufs[t - 4096] = 0;
    } else if (t < 4096 + 262144 + CNT_U32) {
        cnt[t - (4096 + 262144)] = 0;
    }
}

// Stage a 16KB h slice (16 contiguous 1KB rows) into LDS with the
// (row&7)<<4 byte XOR swizzle. 512 threads x 16B x 2 rounds, dense 16B lanes.
template<int ROUNDS>
__device__ __forceinline__ void stage_lds(char* dst, const char* src, int tid) {
    #pragma unroll
    for (int i = 0; i < ROUNDS; ++i) {
        int off = i * 8192 + tid * 16;
        int swz = (off & ~1023) | ((off & 1023) ^ (((off >> 10) & 7) << 4));
        u64x2 v;
        v.x = ld_sys_u64((const ull*)(src + off));
        v.y = ld_sys_u64((const ull*)(src + off + 8));
        *(u64x2*)(dst + swz) = v;
    }
}

// ---- persistent LSTM ----
// NKS: ksteps (full K per wave); KTOT: packed row length; KS: src0/src1 split
template<int NKS, int KTOT, int KS, bool L0>
__device__ __forceinline__ void run_layer(
    int b0, int nt, int tid,
    const float* __restrict__ x,
    const unsigned short* __restrict__ Wp,
    const float* __restrict__ bp,
    unsigned short* h00, unsigned short* h01,
    unsigned short* h10, unsigned short* h11,
    unsigned* slots, int myslot, char* shh)
{
    const int lane = tid & 63, col = lane & 15, quad = lane >> 4;
    const int q = col & 3;
    const int bA = b0 + col;

    // B fragments (weights): one N-tile x full K, register-resident (pinned).
    uint4 Bf[NKS];
    {
        const unsigned short* wrow = Wp + (nt * 16 + col) * KTOT + quad * 8;
        #pragma unroll
        for (int ks = 0; ks < NKS; ++ks)
            Bf[ks] = *(const uint4*)(wrow + ks * 32);
    }
    #pragma unroll
    for (int ks = 0; ks < NKS; ++ks) {
        uint32_t c0 = Bf[ks].x, c1 = Bf[ks].y, c2 = Bf[ks].z, c3 = Bf[ks].w;
        asm volatile("" : "+v"(c0), "+v"(c1), "+v"(c2), "+v"(c3));
        Bf[ks].x = c0; Bf[ks].y = c1; Bf[ks].z = c2; Bf[ks].w = c3;
    }

    const float bias_s = bp[nt * 16 + col];   // one packed gate-row per lane
    f32x4 c = {0.f, 0.f, 0.f, 0.f};           // cell state, x4 lane-replicated

    const int lbase = col * 1024;             // LDS row for this lane's batch
    const int sw = (col & 7) << 4;            // read-side swizzle

    unsigned short* h0b[2] = { h00, h01 };
    unsigned short* h1b[2] = { h10, h11 };
    int rp = 0;

    for (int s = 0; s <= T_STEPS; ++s) {
        const bool active = L0 ? (s < T_STEPS) : (s >= 1);
        if (active) {
            if (L0) {
                stage_lds<2>(shh, (const char*)h0b[rp] + b0 * 1024, tid);          // h0(s-1)
            } else {
                stage_lds<2>(shh,         (const char*)h0b[rp] + b0 * 1024, tid);  // h0(s-1)
                stage_lds<2>(shh + 16384, (const char*)h1b[rp] + b0 * 1024, tid);  // h1(s-2)
            }
        }
        __syncthreads();   // stage visible (drains vm+lgkm for all waves)

        if (active) {
            f32x4 acc = {0.f, 0.f, 0.f, 0.f};
            if (L0) {
                // x-part: plain cached loads (L1-resident across the block's
                // 8 waves), fp32 -> bf16 on the fly
                const float* xb = x + (size_t)bA * (T_STEPS * 256) + (size_t)s * 256;
                #pragma unroll
                for (int ks = 0; ks < 8; ++ks) {
                    const float* p = xb + ks * 32 + quad * 8;
                    float4 lo = *(const float4*)p;
                    float4 hi = *(const float4*)(p + 4);
                    bf16x8 v;
                    v[0]=(__bf16)lo.x; v[1]=(__bf16)lo.y; v[2]=(__bf16)lo.z; v[3]=(__bf16)lo.w;
                    v[4]=(__bf16)hi.x; v[5]=(__bf16)hi.y; v[6]=(__bf16)hi.z; v[7]=(__bf16)hi.w;
                    acc = __builtin_amdgcn_mfma_f32_16x16x32_bf16(
                        v, __builtin_bit_cast(bf16x8, Bf[ks]), acc, 0, 0, 0);
                }
                #pragma unroll
                for (int ks = 8; ks < NKS; ++ks) {
                    int u = (ks * 32 + quad * 8) - KS;
                    bf16x8 a = *(const bf16x8*)(shh + lbase + ((2 * u) ^ sw));
                    acc = __builtin_amdgcn_mfma_f32_16x16x32_bf16(
                        a, __builtin_bit_cast(bf16x8, Bf[ks]), acc, 0, 0, 0);
                }
            } else {
                #pragma unroll
                for (int ks = 0; ks < NKS; ++ks) {
                    int kg = ks * 32 + quad * 8;
                    int buf = (kg < KS) ? 0 : 16384;
                    int u = (kg < KS) ? kg : (kg - KS);
                    bf16x8 a = *(const bf16x8*)(shh + buf + lbase + ((2 * u) ^ sw));
                    acc = __builtin_amdgcn_mfma_f32_16x16x32_bf16(
                        a, __builtin_bit_cast(bf16x8, Bf[ks]), acc, 0, 0, 0);
                }
            }

            // ---- in-wave eltwise: gates of unit u sit in 4 adjacent lanes
            // (col = u_loc*4 + q, q: 0=i,1=f,2=g,3=o); D row quad*4+r = batch.
            unsigned short* hw = L0 ? h0b[rp ^ 1] : h1b[rp ^ 1];
            #pragma unroll
            for (int r = 0; r < 4; ++r) {
                float v = acc[r] + bias_s;
                float sv = sigm(v);
                float av = (q == 2) ? tanh_f(v) : sv;     // own activation
                float s1 = __shfl_xor(av, 1);
                float a  = (q & 1) ? s1 : av;             // q01: si ; q23: tg
                float b_ = (q & 1) ? av : s1;             // q01: sf ; q23: so
                float t  = __shfl_xor(a, 2);              // q01<-tg ; q23<-si
                float u2 = __shfl_xor(b_, 2);             // q01<-so ; q23<-sf
                float ig = (q < 2) ? a  : t;
                float fg = (q < 2) ? b_ : u2;
                float gg = (q < 2) ? t  : a;
                float og = (q < 2) ? u2 : b_;
                c[r] = fg * c[r] + ig * gg;
                float h = og * tanh_f(c[r]);
                // pack 2 units (col, col+4) -> one u32 sc01 store by col%8==0
                unsigned hv = (unsigned)f2bf(h);
                unsigned pv = (unsigned)__shfl_xor((int)hv, 4);
                if ((col & 7) == 0) {
                    unsigned pk = hv | (pv << 16);
                    st_sys_u32((unsigned*)(hw + (b0 + quad * 4 + r) * 512
                                              + nt * 4 + (col >> 2)), pk);
                }
            }
        }
        // release: drain own vmem (h stores acked at IF$), then post flag
        asm volatile("s_waitcnt vmcnt(0)" ::: "memory");
        __syncthreads();
        if (tid == 0)
            st_sys_u32(slots + myslot, (unsigned)(s + 1));
        // wave0 ONLY: poll the group's 32 slots (one 128B line)
        if (tid < 64) {
            const unsigned tgt = (unsigned)(s + 1);
            for (;;) {
                unsigned v = ld_sys_u32(slots + (lane & 31));
                if (__all((int)(v >= tgt))) break;
                __builtin_amdgcn_s_sleep(1);
            }
        }
        asm volatile("" ::: "memory");
        __syncthreads();
        rp ^= 1;
    }
}

__global__ __launch_bounds__(NTHR) void lstm_persistent(
    const float* __restrict__ x,
    const unsigned short* __restrict__ Wp0, const unsigned short* __restrict__ Wp1,
    const float* __restrict__ bp0, const float* __restrict__ bp1,
    unsigned short* __restrict__ hb, unsigned* __restrict__ cnt)
{
    __shared__ alignas(16) char shh[32768];   // staged h (l0 uses first 16KB)
    const int bid   = blockIdx.x;
    const int g     = bid & 7;          // batch-tile group (independent domain)
    const int rest  = bid >> 3;         // 0..31: pid within group
    const int layer = rest & 1;
    const int nb    = rest >> 1;        // 0..15: N-block (8 N-tiles each)
    const int b0    = g * 16;
    const int tid   = threadIdx.x;
    const int w     = tid >> 6;         // wave 0..7
    const int nt    = nb * 8 + w;       // N-tile 0..127 (16 packed gate rows)

    unsigned* slots = cnt + g * 32;
    const int myslot = rest;

    unsigned short* h00 = hb;
    unsigned short* h01 = hb + 65536;
    unsigned short* h10 = hb + 131072;
    unsigned short* h11 = hb + 196608;

    if (layer == 0)
        run_layer<24, 768, 256, true >(b0, nt, tid, x, Wp0, bp0, h00, h01, h10, h11, slots, myslot, shh);
    else
        run_layer<32, 1024, 512, false>(b0, nt, tid, x, Wp1, bp1, h00, h01, h10, h11, slots, myslot, shh);
}

// ---- final FC head: logits[b] = h1_T[b,:] . fc_w + fc_b ----
__global__ void k_fc(const unsigned short* __restrict__ h1, const float* __restrict__ fcw,
                     const float* __restrict__ fcb, float* __restrict__ out)
{
    int b = threadIdx.x;
    if (b < 128) {
        const unsigned short* hr = h1 + b * 512;
        float acc = 0.f;
        for (int u = 0; u < 512; ++u) acc += bf2f(hr[u]) * fcw[u];
        out[b] = acc + fcb[0];
    }
}

extern "C" void kernel_launch(void* const* d_in, const int* in_sizes, int n_in,
                              void* d_out, int out_size, void* d_ws, size_t ws_size,
                              hipStream_t stream)
{
    const float* x    = (const float*)d_in[0];
    const float* Wih0 = (const float*)d_in[1];
    const float* Whh0 = (const float*)d_in[2];
    const float* bih0 = (const float*)d_in[3];
    const float* bhh0 = (const float*)d_in[4];
    const float* Wih1 = (const float*)d_in[5];
    const float* Whh1 = (const float*)d_in[6];
    const float* bih1 = (const float*)d_in[7];
    const float* bhh1 = (const float*)d_in[8];
    const float* fcw  = (const float*)d_in[9];
    const float* fcb  = (const float*)d_in[10];

    char* ws = (char*)d_ws;
    unsigned short* Wp0 = (unsigned short*)(ws + WS_WP0);
    unsigned short* Wp1 = (unsigned short*)(ws + WS_WP1);
    float* bp0 = (float*)(ws + WS_BP0);
    float* bp1 = (float*)(ws + WS_BP1);
    unsigned short* hb = (unsigned short*)(ws + WS_H);
    unsigned* cnt = (unsigned*)(ws + WS_CNT);

    const int npack = 2048 * 768 + 2048 * 1024;
    k_pack<<<(npack + 255) / 256, 256, 0, stream>>>(Wih0, Whh0, Wih1, Whh1, Wp0, Wp1);
    const int nmisc = 4096 + 262144 + CNT_U32;
    k_misc<<<(nmisc + 255) / 256, 256, 0, stream>>>(bih0, bhh0, bih1, bhh1, bp0, bp1, hb, cnt);

    lstm_persistent<<<NBLK, NTHR, 0, stream>>>(x, Wp0, Wp1, bp0, bp1, hb, cnt);

    // final h1 lands in ping-pong buffer index 1 (written at macro-step s=1024)
    k_fc<<<1, 128, 0, stream>>>(hb + 196608, fcw, fcb, (float*)d_out);
}

// Round 9
// 5841.790 us; speedup vs baseline: 2.1439x; 1.4763x over previous
//
#include <hip/hip_runtime.h>
#include <stdint.h>

// LSTMClassifier: 2-layer LSTM (B=128,T=1024,I=256,H=512) + FC(512->1).
// Persistent grid-resident kernel. R14 = R6 data path + compute byte-for-byte
// (proven fastest: per-lane strided 8B sc01 IF$ loads, paired 4B sc01 stores,
// 4-wave K-split + LDS red buffer, ONE polling wave, 3 barriers/step, no
// fences), with the group-wide rendezvous replaced by per-edge dataflow:
//   - 4-deep h rings per layer (R10 layout) give anti-overwrite slack.
//   - poll thresholds = true deps only (own slot masked):
//       l0 @ s: l0 peers >= s  (h0(s-1)),  l1 peers >= s-2 (ring, slack-2)
//       l1 @ s: l0 peers >= s  (h0(s-1)),  l1 peers >= s   (h1(s-2), lag-1)
//     -> l0's per-step wait is max over 16 blocks (not 64); l1 decouples,
//     riding 1 step behind. Attacks the rendezvous-skew term (max-of-64
//     jitter) that the counters say dominates (compute = 0.37us of 7.5us).
//   - l0's x loads issue BEFORE the poll barrier (overlap detect window).
// R10's regression was 4-wave polling (poll storm) + lag-2 misthresholds;
// here polling stays wave0-only and thresholds are the audited set:
//   l0@s writes h0(s) slot s&3 destroying h0(s-4): readers l0@s-3 (l0>=s-2
//   subset of >=s OK) and l1@s-3 (l1>=s-2 polled exactly). l1@s writes
//   h1(s-1) destroying h1(s-5): reader l1@s-3 (l1>=s covers).
//
// ws layout (bytes):
//   Wp0 [2048][768]  bf16 packed rows r=u*4+q  (cols: 0..255=W_ih0, 256..767=W_hh0)
//   Wp1 [2048][1024] bf16 packed                (cols: 0..511=W_ih1, 512..1023=W_hh1)
//   bp0/bp1 [2048] f32 (b_ih+b_hh, packed order)
//   h    ushort[8][128*512]: h0 ring slots 0..3, then h1 ring slots 0..3
//   cnt  flag slots: 8 groups x 64 dwords (one single-writer slot per block)

#define T_STEPS 1024
#define NBLK 512
#define NTHR 256

#define WS_WP0   0u
#define WS_WP1   3145728u
#define WS_BP0   7340032u
#define WS_BP1   7348224u
#define WS_H     7356416u
#define WS_CNT   8404992u
#define CNT_U32  512         // 8 groups x 64 slots

typedef __bf16 bf16x8 __attribute__((ext_vector_type(8)));
typedef float  f32x4  __attribute__((ext_vector_type(4)));
typedef unsigned long long ull;
typedef ull u64x2 __attribute__((ext_vector_type(2)));

__device__ __forceinline__ unsigned short f2bf(float f) {
    union { float f; uint32_t u; } a; a.f = f;
    uint32_t r = a.u + 0x7fffu + ((a.u >> 16) & 1u);
    return (unsigned short)(r >> 16);
}
__device__ __forceinline__ float bf2f(unsigned short u) {
    union { uint32_t u; float f; } a; a.u = ((uint32_t)u) << 16; return a.f;
}
__device__ __forceinline__ float sigm(float x)  { return 1.f / (1.f + __expf(-x)); }
__device__ __forceinline__ float tanh_f(float x){ return 2.f / (1.f + __expf(-2.f * x)) - 1.f; }

// IF$-coherent (L1+L2-bypassing) accessors: relaxed system atomics -> sc0 sc1
__device__ __forceinline__ bf16x8 ld_h16(const unsigned short* p) {
    u64x2 t;
    t.x = __hip_atomic_load((const ull*)p,       __ATOMIC_RELAXED, __HIP_MEMORY_SCOPE_SYSTEM);
    t.y = __hip_atomic_load((const ull*)(p + 4), __ATOMIC_RELAXED, __HIP_MEMORY_SCOPE_SYSTEM);
    return __builtin_bit_cast(bf16x8, t);
}
__device__ __forceinline__ void st_sys_u32(unsigned* p, unsigned v) {
    __hip_atomic_store(p, v, __ATOMIC_RELAXED, __HIP_MEMORY_SCOPE_SYSTEM);
}
__device__ __forceinline__ unsigned ld_sys_u32(const unsigned* p) {
    return __hip_atomic_load(p, __ATOMIC_RELAXED, __HIP_MEMORY_SCOPE_SYSTEM);
}

// ---- pre-pack weights to bf16, gate-interleaved rows r = u*4 + q (q: i,f,g,o) ----
__global__ void k_pack(const float* __restrict__ Wih0, const float* __restrict__ Whh0,
                       const float* __restrict__ Wih1, const float* __restrict__ Whh1,
                       unsigned short* __restrict__ Wp0, unsigned short* __restrict__ Wp1)
{
    int t = blockIdx.x * blockDim.x + threadIdx.x;
    const int N0 = 2048 * 768;
    const int N1 = 2048 * 1024;
    if (t < N0) {
        int r = t / 768, k = t - r * 768;
        int u = r >> 2, q = r & 3, row = q * 512 + u;
        float v = (k < 256) ? Wih0[row * 256 + k] : Whh0[row * 512 + (k - 256)];
        Wp0[t] = f2bf(v);
    } else if (t < N0 + N1) {
        int t2 = t - N0;
        int r = t2 >> 10, k = t2 & 1023;
        int u = r >> 2, q = r & 3, row = q * 512 + u;
        float v = (k < 512) ? Wih1[row * 512 + k] : Whh1[row * 512 + (k - 512)];
        Wp1[t2] = f2bf(v);
    }
}

// ---- biases (packed), zero h ring buffers, zero flag slots ----
__global__ void k_misc(const float* __restrict__ bih0, const float* __restrict__ bhh0,
                       const float* __restrict__ bih1, const float* __restrict__ bhh1,
                       float* __restrict__ bp0, float* __restrict__ bp1,
                       unsigned short* __restrict__ hbufs, unsigned* __restrict__ cnt)
{
    int t = blockIdx.x * blockDim.x + threadIdx.x;
    if (t < 2048) {
        int u = t >> 2, q = t & 3, row = q * 512 + u;
        bp0[t] = bih0[row] + bhh0[row];
    } else if (t < 4096) {
        int r = t - 2048; int u = r >> 2, q = r & 3, row = q * 512 + u;
        bp1[r] = bih1[row] + bhh1[row];
    } else if (t < 4096 + 524288) {
        hbufs[t - 4096] = 0;
    } else if (t < 4096 + 524288 + CNT_U32) {
        cnt[t - (4096 + 524288)] = 0;
    }
}

// ---- persistent LSTM ----
// NKW: ksteps per wave; KTOT: total K; KS: boundary src0/src1; L0: layer-0 flag
// h rings: h0(t) at hb + (t&3)*65536, h1(t) at hb + 262144 + (t&3)*65536
template<int NKW, int KTOT, int KS, bool L0>
__device__ __forceinline__ void run_layer(
    int b0, int ut0, int g0, int w, int col, int quad, int tid,
    const float* __restrict__ x,
    const unsigned short* __restrict__ Wp,
    const float* __restrict__ bp,
    unsigned short* __restrict__ hb,
    unsigned* slots, int myslot,
    float (*red)[16][68])
{
    const int bA   = b0 + col;  // A-fragment row (batch index)
    const int lane = tid & 63;

    // B fragments (weights) -> register-resident for the whole run (pinned).
    uint4 Bf[4][NKW];
    #pragma unroll
    for (int f = 0; f < 4; ++f) {
        const unsigned short* wrow = Wp + (g0 + f * 16 + col) * KTOT + w * (NKW * 32) + quad * 8;
        #pragma unroll
        for (int ks = 0; ks < NKW; ++ks)
            Bf[f][ks] = *(const uint4*)(wrow + ks * 32);
    }
    #pragma unroll
    for (int f = 0; f < 4; ++f) {
        #pragma unroll
        for (int ks = 0; ks < NKW; ++ks) {
            uint32_t c0 = Bf[f][ks].x, c1 = Bf[f][ks].y, c2 = Bf[f][ks].z, c3 = Bf[f][ks].w;
            asm volatile("" : "+v"(c0), "+v"(c1), "+v"(c2), "+v"(c3));
            Bf[f][ks].x = c0; Bf[f][ks].y = c1; Bf[f][ks].z = c2; Bf[f][ks].w = c3;
        }
    }

    const int bl = tid >> 4, ul = tid & 15;      // elementwise domain: 16 batch x 16 units
    const f32x4 bias = *(const f32x4*)(bp + g0 + ul * 4);
    float c = 0.f;                               // cell state, register-resident

    // Per-kstep A source offsets (frag never straddles the KS boundary: 32 | KS)
    int  offA[NKW];
    bool s0[NKW];
    #pragma unroll
    for (int ks = 0; ks < NKW; ++ks) {
        int kg = w * (NKW * 32) + ks * 32 + quad * 8;
        if (kg < KS) { s0[ks] = true;  offA[ks] = L0 ? (bA * (T_STEPS * 256) + kg) : (bA * 512 + kg); }
        else         { s0[ks] = false; offA[ks] = bA * 512 + (kg - KS); }
    }

    // SMAX: l0 computes s=0..T-1; l1 computes h1(s-1) for s=1..T
    const int SMAX = L0 ? (T_STEPS - 1) : T_STEPS;

    for (int s = 0; s <= SMAX; ++s) {
        const bool active = L0 || (s >= 1);
        bf16x8 Af[NKW];

        if (L0) {
            // x-part first: static data, overlaps the poll detect window
            const float* xb = x + s * 256;
            #pragma unroll
            for (int ks = 0; ks < NKW; ++ks) {
                if (s0[ks]) {
                    const float* p = xb + offA[ks];
                    float4 lo = *(const float4*)p;
                    float4 hi = *(const float4*)(p + 4);
                    bf16x8 v;
                    v[0]=(__bf16)lo.x; v[1]=(__bf16)lo.y; v[2]=(__bf16)lo.z; v[3]=(__bf16)lo.w;
                    v[4]=(__bf16)hi.x; v[5]=(__bf16)hi.y; v[6]=(__bf16)hi.z; v[7]=(__bf16)hi.w;
                    Af[ks] = v;
                }
            }
        }

        // wave0: dataflow poll. Thresholds (slot layer = lane&1):
        //   L0: l0 peers >= s, l1 peers >= s-2 (ring slack). L1: all >= s.
        if (s >= 1 && tid < 64) {
            int tgt = L0 ? (s - ((lane & 1) << 1)) : s;
            if (lane == myslot) tgt = (int)0x80000000;
            for (;;) {
                int v = (int)ld_sys_u32(slots + lane);
                if (__all(v >= tgt)) break;
                __builtin_amdgcn_s_sleep(1);
            }
        }
        __syncthreads();   // deps satisfied for everyone

        if (active) {
            if (L0) {
                const unsigned short* hr = hb + (((unsigned)(s + 3)) & 3u) * 65536; // h0(s-1)
                #pragma unroll
                for (int ks = 0; ks < NKW; ++ks)
                    if (!s0[ks]) Af[ks] = ld_h16(hr + offA[ks]);
            } else {
                const unsigned short* h0r = hb + (((unsigned)(s + 3)) & 3u) * 65536;           // h0(s-1)
                const unsigned short* h1r = hb + 262144 + (((unsigned)(s + 2)) & 3u) * 65536;  // h1(s-2)
                #pragma unroll
                for (int ks = 0; ks < NKW; ++ks)
                    Af[ks] = ld_h16((s0[ks] ? h0r : h1r) + offA[ks]);
            }

            f32x4 acc[4] = { f32x4{0,0,0,0}, f32x4{0,0,0,0}, f32x4{0,0,0,0}, f32x4{0,0,0,0} };
            #pragma unroll
            for (int ks = 0; ks < NKW; ++ks) {
                #pragma unroll
                for (int f = 0; f < 4; ++f)
                    acc[f] = __builtin_amdgcn_mfma_f32_16x16x32_bf16(
                        Af[ks], __builtin_bit_cast(bf16x8, Bf[f][ks]), acc[f], 0, 0, 0);
            }
            // Dump partials: D row=quad*4+r (batch), col=f*16+col (packed gate)
            #pragma unroll
            for (int f = 0; f < 4; ++f) {
                #pragma unroll
                for (int r = 0; r < 4; ++r)
                    red[w][quad * 4 + r][f * 16 + col] = acc[f][r];
            }
        }
        __syncthreads();
        if (active) {
            f32x4 g = bias;
            #pragma unroll
            for (int ww = 0; ww < 4; ++ww)
                g += *(const f32x4*)&red[ww][bl][ul * 4];
            float ig = sigm(g[0]), fg = sigm(g[1]), gc = tanh_f(g[2]), og = sigm(g[3]);
            c = fg * c + ig * gc;
            float h = og * tanh_f(c);
            // pack adjacent ul lanes -> one 4B IF$-coherent store per pair
            unsigned short hv = f2bf(h);
            unsigned short pv = (unsigned short)__shfl_xor((int)hv, 1);
            if (!(ul & 1)) {
                unsigned short* hw = L0
                    ? (hb + (((unsigned)s) & 3u) * 65536)                       // h0(s)
                    : (hb + 262144 + (((unsigned)(s + 3)) & 3u) * 65536);       // h1(s-1)
                unsigned pk = (unsigned)hv | ((unsigned)pv << 16);
                st_sys_u32((unsigned*)(hw + (b0 + bl) * 512 + ut0 + ul), pk);
            }
        }
        // release: drain own vmem (stores acked at IF$), then post flag
        asm volatile("s_waitcnt vmcnt(0)" ::: "memory");
        __syncthreads();
        if (tid == 0)
            st_sys_u32(slots + myslot, (unsigned)(s + 1));
    }
}

__global__ __launch_bounds__(NTHR, 2) void lstm_persistent(
    const float* __restrict__ x,
    const unsigned short* __restrict__ Wp0, const unsigned short* __restrict__ Wp1,
    const float* __restrict__ bp0, const float* __restrict__ bp1,
    unsigned short* __restrict__ hb, unsigned* __restrict__ cnt)
{
    __shared__ alignas(16) float red[4][16][68];   // 4 K-split waves x [16b][64g(+pad)]
    const int bid   = blockIdx.x;
    const int g     = bid & 7;          // batch-tile group (independent flag domain)
    const int rest  = bid >> 3;         // 0..63: pid within group
    const int layer = rest & 1;
    const int ut    = rest >> 1;        // 0..31 unit-tile
    const int b0    = g * 16;
    const int ut0   = ut * 16;
    const int g0    = ut * 64;          // packed gate-row base (= ut0*4)
    const int tid   = threadIdx.x;
    const int w = tid >> 6, lane = tid & 63, col = lane & 15, quad = lane >> 4;

    unsigned* slots = cnt + g * 64;
    const int myslot = rest;

    if (layer == 0)
        run_layer<6, 768, 256, true >(b0, ut0, g0, w, col, quad, tid, x, Wp0, bp0, hb, slots, myslot, red);
    else
        run_layer<8, 1024, 512, false>(b0, ut0, g0, w, col, quad, tid, x, Wp1, bp1, hb, slots, myslot, red);
}

// ---- final FC head: logits[b] = h1_T[b,:] . fc_w + fc_b ----
// final h1(1023) lives in h1 ring slot 1023&3 = 3
__global__ void k_fc(const unsigned short* __restrict__ h1, const float* __restrict__ fcw,
                     const float* __restrict__ fcb, float* __restrict__ out)
{
    int b = threadIdx.x;
    if (b < 128) {
        const unsigned short* hr = h1 + b * 512;
        float acc = 0.f;
        for (int u = 0; u < 512; ++u) acc += bf2f(hr[u]) * fcw[u];
        out[b] = acc + fcb[0];
    }
}

extern "C" void kernel_launch(void* const* d_in, const int* in_sizes, int n_in,
                              void* d_out, int out_size, void* d_ws, size_t ws_size,
                              hipStream_t stream)
{
    const float* x    = (const float*)d_in[0];
    const float* Wih0 = (const float*)d_in[1];
    const float* Whh0 = (const float*)d_in[2];
    const float* bih0 = (const float*)d_in[3];
    const float* bhh0 = (const float*)d_in[4];
    const float* Wih1 = (const float*)d_in[5];
    const float* Whh1 = (const float*)d_in[6];
    const float* bih1 = (const float*)d_in[7];
    const float* bhh1 = (const float*)d_in[8];
    const float* fcw  = (const float*)d_in[9];
    const float* fcb  = (const float*)d_in[10];

    char* ws = (char*)d_ws;
    unsigned short* Wp0 = (unsigned short*)(ws + WS_WP0);
    unsigned short* Wp1 = (unsigned short*)(ws + WS_WP1);
    float* bp0 = (float*)(ws + WS_BP0);
    float* bp1 = (float*)(ws + WS_BP1);
    unsigned short* hb = (unsigned short*)(ws + WS_H);
    unsigned* cnt = (unsigned*)(ws + WS_CNT);

    const int npack = 2048 * 768 + 2048 * 1024;
    k_pack<<<(npack + 255) / 256, 256, 0, stream>>>(Wih0, Whh0, Wih1, Whh1, Wp0, Wp1);
    const int nmisc = 4096 + 524288 + CNT_U32;
    k_misc<<<(nmisc + 255) / 256, 256, 0, stream>>>(bih0, bhh0, bih1, bhh1, bp0, bp1, hb, cnt);

    lstm_persistent<<<NBLK, NTHR, 0, stream>>>(x, Wp0, Wp1, bp0, bp1, hb, cnt);

    // final h1(1023) is in h1 ring slot 3: hb + 262144 + 3*65536
    k_fc<<<1, 128, 0, stream>>>(hb + 262144 + 196608, fcw, fcb, (float*)d_out);
}